// Round 6
// baseline (43.808 us; speedup 1.0000x reference)
//
#include <hip/hip_runtime.h>
#include <math.h>

#define GH 5
#define GW 10
#define HW 50            // GH*GW
#define CPA 85           // channels per anchor (5 + 80)
#define SLICE 12750      // 255 * 50 floats per batch
#define NT 8             // targets per batch
#define NB 4             // batches per block
#define TT (NB*NT)       // 32 targets per block
#define IOU_THR 0.3f

__device__ __forceinline__ float softplusf(float x) {
    return fmaxf(x, 0.0f) + log1pf(expf(-fabsf(x)));   // log(1+e^x), stable
}
__device__ __forceinline__ float sigmoidf(float x) {
    return 1.0f / (1.0f + expf(-x));
}

// Four batches per block: ~11 outstanding gather loads per thread, and the
// fixed per-block costs (2 barrier latency bubbles, metadata, loss tail,
// epilogue) amortize over 4x the bytes.
__global__ __launch_bounds__(256) void yolo_main(
    const float* __restrict__ preds,
    const float* __restrict__ targets,
    const float* __restrict__ anchors,
    float* __restrict__ part, int B)   // part[block*4+..] = coord_raw, obj, noobj_raw, cls_raw
{
    __shared__ float ptile[TT][88];   // 85 gathered channels x 32 targets
    __shared__ float stgt[TT][4];
    __shared__ int   soff[TT];        // element offset of channel-0 (best anchor, cell)
    __shared__ int   scls[TT];
    __shared__ int   svalid[TT];
    __shared__ float Ssh[NB];
    __shared__ float wsum[4][NB];
    __shared__ float accS[4];

    const int b0  = blockIdx.x * NB;
    const int tid = threadIdx.x;

    // ---- issue obj-channel loads RAW (600 loads, <=3 per thread) ----
    float ov[3];
    #pragma unroll
    for (int r = 0; r < 3; ++r) {
        int k = tid + r * 256;
        ov[r] = 0.0f;
        if (k < NB * 150) {
            int bb  = k / 150, rem = k - bb * 150;
            int a   = rem / 50, yx  = rem - a * 50;
            int bidx = min(b0 + bb, B - 1);
            ov[r] = preds[(size_t)bidx * SLICE + (a * CPA + 4) * HW + yx];
        }
    }

    // ---- per-target metadata (threads 0..31) ----
    if (tid < TT) {
        int bb = tid >> 3, tt = tid & 7;
        int bidx = min(b0 + bb, B - 1);
        const float* tg = targets + ((size_t)bidx * NT + tt) * 5;
        float cls = tg[0], tx = tg[1], ty = tg[2], tw = tg[3], th = tg[4];
        int gx = (int)floorf(tx * (float)GW);
        int gy = (int)floorf(ty * (float)GH);
        float best_iou = -1.0f; int best_a = 0;
        #pragma unroll
        for (int a = 0; a < 3; ++a) {
            float aw = anchors[2*a], ah = anchors[2*a+1];
            float inter = fminf(tw, aw) * fminf(th, ah);
            float uni   = tw*th + aw*ah - inter;
            float iou   = inter / (uni + 1e-6f);
            if (iou > best_iou) { best_iou = iou; best_a = a; }  // first-max wins
        }
        int valid = (gx < GW) && (gy < GH) && (best_iou >= IOU_THR) && (b0 + bb < B);
        int gxc = min(max(gx, 0), GW-1);
        int gyc = min(max(gy, 0), GH-1);
        float aw_s = anchors[2*best_a], ah_s = anchors[2*best_a+1];
        stgt[tid][0] = tx * (float)GW - (float)gx;
        stgt[tid][1] = ty * (float)GH - (float)gy;
        stgt[tid][2] = logf(tw / aw_s + 1e-6f);
        stgt[tid][3] = logf(th / ah_s + 1e-6f);
        scls[tid]   = (int)cls;
        svalid[tid] = valid;
        soff[tid]   = valid ? (bidx * SLICE + best_a * CPA * HW + gyc * GW + gxc) : 0;
    }
    if (tid < 4) accS[tid] = 0.0f;
    __syncthreads();

    // ---- direct gather: 2720 scattered loads (10 unrolled + tail of 160) ----
    {
        int i = tid;
        #pragma unroll
        for (int r = 0; r < 10; ++r) {
            int t = i / CPA, cc = i - t * CPA;
            ptile[t][cc] = preds[soff[t] + cc * HW];
            i += 256;
        }
        if (i < TT * CPA) {
            int t = i / CPA, cc = i - t * CPA;
            ptile[t][cc] = preds[soff[t] + cc * HW];
        }
    }

    // ---- obj softplus + per-batch S reduce (hides under gather latency) ----
    float s[NB] = {0.f, 0.f, 0.f, 0.f};
    #pragma unroll
    for (int r = 0; r < 3; ++r) {
        int k = tid + r * 256;
        if (k < NB * 150) {
            int bb = k / 150;
            s[bb] += softplusf(sigmoidf(ov[r]));
        }
    }
    #pragma unroll
    for (int off = 32; off > 0; off >>= 1) {
        #pragma unroll
        for (int bb = 0; bb < NB; ++bb) s[bb] += __shfl_xor(s[bb], off);
    }
    const int wid = tid >> 6, lane = tid & 63;
    if (lane == 0) {
        #pragma unroll
        for (int bb = 0; bb < NB; ++bb) wsum[wid][bb] = s[bb];
    }
    __syncthreads();            // also publishes ptile
    if (tid < NB) Ssh[tid] = wsum[0][tid] + wsum[1][tid] + wsum[2][tid] + wsum[3][tid];
    __syncthreads();

    // ---- per-target losses: one wave per target (4 waves x 8 rounds) ----
    for (int t = wid; t < TT; t += 4) {
        if (!svalid[t]) continue;
        float v0 = ptile[t][lane];                                  // ch 0..63
        float v1 = (lane < CPA - 64) ? ptile[t][64 + lane] : 0.0f;  // ch 64..84
        // logsumexp over class logits (ch 5..84)
        float m = -INFINITY;
        if (lane >= 5)        m = v0;
        if (lane < CPA - 64)  m = fmaxf(m, v1);
        #pragma unroll
        for (int off = 32; off > 0; off >>= 1) m = fmaxf(m, __shfl_xor(m, off));
        float sx = 0.0f, csq = 0.0f;
        if (lane >= 5)        sx += expf(v0 - m);
        if (lane < CPA - 64)  sx += expf(v1 - m);
        if (lane < 4) { float d = v0 - stgt[t][lane]; csq = d * d; }
        #pragma unroll
        for (int off = 32; off > 0; off >>= 1) {
            sx  += __shfl_xor(sx, off);
            csq += __shfl_xor(csq, off);
        }
        float p4 = __shfl(v0, 4);
        int cch = 5 + scls[t];
        float pl = (cch < 64) ? __shfl(v0, cch) : __shfl(v1, cch - 64);
        float ce = m + logf(sx) - pl;
        float z    = sigmoidf(p4);
        float spz  = softplusf(z);
        float spnz = softplusf(-z);
        if (lane == 0) {
            int bb = t >> 3;
            atomicAdd(&accS[0], csq);          // LDS atomics — cheap
            atomicAdd(&accS[1], spnz);
            atomicAdd(&accS[2], Ssh[bb] - spz);
            atomicAdd(&accS[3], ce);
        }
    }
    __syncthreads();
    // ---- one plain float4-sized store per block: NO global atomics ----
    if (tid < 4) part[(size_t)blockIdx.x * 4 + tid] = accS[tid];
}

__global__ __launch_bounds__(1024) void yolo_reduce(
    const float4* __restrict__ part, int nb,
    float* __restrict__ out, float denom)
{
    __shared__ float wsum[16][4];
    float c0 = 0.f, c1 = 0.f, c2 = 0.f, c3 = 0.f;
    for (int i = threadIdx.x; i < nb; i += 1024) {
        float4 v = part[i];
        c0 += v.x; c1 += v.y; c2 += v.z; c3 += v.w;
    }
    #pragma unroll
    for (int off = 32; off > 0; off >>= 1) {
        c0 += __shfl_xor(c0, off); c1 += __shfl_xor(c1, off);
        c2 += __shfl_xor(c2, off); c3 += __shfl_xor(c3, off);
    }
    int w = threadIdx.x >> 6;
    if ((threadIdx.x & 63) == 0) {
        wsum[w][0] = c0; wsum[w][1] = c1; wsum[w][2] = c2; wsum[w][3] = c3;
    }
    __syncthreads();
    if (threadIdx.x == 0) {
        float a0 = 0.f, a1 = 0.f, a2 = 0.f, a3 = 0.f;
        #pragma unroll
        for (int i = 0; i < 16; ++i) {
            a0 += wsum[i][0]; a1 += wsum[i][1]; a2 += wsum[i][2]; a3 += wsum[i][3];
        }
        float lc   = a0 / denom;
        float lo   = a1;
        float ln   = 0.5f * a2;
        float lcls = a3 / denom;
        float tot  = 5.0f * lc + lo + 0.5f * ln + lcls;
        out[0] = tot; out[1] = lc; out[2] = lo; out[3] = ln; out[4] = lcls;
    }
}

extern "C" void kernel_launch(void* const* d_in, const int* in_sizes, int n_in,
                              void* d_out, int out_size, void* d_ws, size_t ws_size,
                              hipStream_t stream) {
    const float* preds   = (const float*)d_in[0];
    const float* targets = (const float*)d_in[1];
    const float* anchors = (const float*)d_in[2];
    float* out  = (float*)d_out;
    float* part = (float*)d_ws;           // 4 floats per block, fully overwritten

    int B = in_sizes[0] / SLICE;   // 4096
    int grid = (B + NB - 1) / NB;  // 4 batches per block

    yolo_main<<<grid, 256, 0, stream>>>(preds, targets, anchors, part, B);
    yolo_reduce<<<1, 1024, 0, stream>>>((const float4*)part, grid, out, (float)B * (float)NT);
}

// Round 7
// 42.044 us; speedup vs baseline: 1.0419x; 1.0419x over previous
//
#include <hip/hip_runtime.h>
#include <math.h>

#define GH 5
#define GW 10
#define HW 50            // GH*GW
#define CPA 85           // channels per anchor (5 + 80)
#define SLICE 12750      // 255 * 50 floats per batch
#define NT 8             // targets per batch
#define WPB 4            // waves per block = batches per block
#define IOU_THR 0.3f

__device__ __forceinline__ float softplusf(float x) {
    return fmaxf(x, 0.0f) + log1pf(expf(-fabsf(x)));   // log(1+e^x), stable
}
__device__ __forceinline__ float sigmoidf(float x) {
    return 1.0f / (1.0f + expf(-x));
}

// One WAVE per batch, barrier-free. Per-wave LDS ops are processed in issue
// order, so a wave that ds_writes metadata/ptile and later ds_reads it needs
// no __syncthreads — all cross-lane transport stays inside the wave.
__global__ __launch_bounds__(256) void yolo_main(
    const float* __restrict__ preds,
    const float* __restrict__ targets,
    const float* __restrict__ anchors,
    float4* __restrict__ part, int B)   // part[b] = {coord_raw, obj, noobj_raw, cls_raw}
{
    __shared__ float ptile[WPB*NT][88];   // 85 gathered channels per target
    __shared__ float stgt[WPB*NT][4];
    __shared__ int   soff[WPB*NT];        // elem offset of (batch, best anchor, cell)
    __shared__ int   scls[WPB*NT];
    __shared__ int   sval[WPB*NT];

    const int  tid  = threadIdx.x;
    const int  wid  = tid >> 6;
    const int  lane = tid & 63;
    const int  b    = blockIdx.x * WPB + wid;
    const bool bv   = (b < B);
    const int  bidx = min(b, B - 1);
    const float* base = preds + (size_t)bidx * SLICE;

    // ---- issue obj-channel loads (150 per wave, <=3 per lane) ----
    const int k1 = lane + 64, k2 = lane + 128;
    float ov0 = base[((lane / 50) * CPA + 4) * HW + (lane % 50)];
    float ov1 = base[((k1 / 50) * CPA + 4) * HW + (k1 % 50)];
    float ov2 = (k2 < 150) ? base[((k2 / 50) * CPA + 4) * HW + (k2 % 50)] : 0.0f;

    // ---- per-target metadata: lanes 0..7 of this wave ----
    if (lane < NT) {
        int tl = wid * NT + lane;
        const float* tg = targets + ((size_t)bidx * NT + lane) * 5;
        float cls = tg[0], tx = tg[1], ty = tg[2], tw = tg[3], th = tg[4];
        int gx = (int)floorf(tx * (float)GW);
        int gy = (int)floorf(ty * (float)GH);
        float best = -1.0f; int ba = 0;
        #pragma unroll
        for (int a = 0; a < 3; ++a) {
            float aw = anchors[2*a], ah = anchors[2*a+1];
            float inter = fminf(tw, aw) * fminf(th, ah);
            float uni   = tw*th + aw*ah - inter;
            float iou   = inter / (uni + 1e-6f);
            if (iou > best) { best = iou; ba = a; }   // first-max wins
        }
        int valid = (gx < GW) && (gy < GH) && (best >= IOU_THR) && bv;
        int gxc = min(max(gx, 0), GW-1);
        int gyc = min(max(gy, 0), GH-1);
        float aws = anchors[2*ba], ahs = anchors[2*ba+1];
        stgt[tl][0] = tx * (float)GW - (float)gx;
        stgt[tl][1] = ty * (float)GH - (float)gy;
        stgt[tl][2] = logf(tw / aws + 1e-6f);
        stgt[tl][3] = logf(th / ahs + 1e-6f);
        scls[tl] = (int)cls;
        sval[tl] = valid;
        soff[tl] = valid ? (bidx * SLICE + (ba * CPA) * HW + gyc * GW + gxc) : 0;
    }
    // no barrier: same-wave LDS write -> read is in-order

    // ---- gather: 680 scattered loads per wave (10 full rounds + 40) ----
    #pragma unroll
    for (int r = 0; r < 11; ++r) {
        int i = lane + r * 64;
        if (i < NT * CPA) {
            int t8 = i / CPA, cc = i - t8 * CPA;
            int tl = wid * NT + t8;
            ptile[tl][cc] = preds[(size_t)soff[tl] + (size_t)cc * HW];
        }
    }

    // ---- obj softplus + per-wave S reduce (hides under gather latency) ----
    float s = softplusf(sigmoidf(ov0)) + softplusf(sigmoidf(ov1));
    if (k2 < 150) s += softplusf(sigmoidf(ov2));
    #pragma unroll
    for (int off = 32; off > 0; off >>= 1) s += __shfl_xor(s, off);
    const float S = s;

    // ---- per-target losses, accumulated in registers (wave-uniform) ----
    float a_coord = 0.f, a_obj = 0.f, a_noobj = 0.f, a_cls = 0.f;
    #pragma unroll
    for (int t8 = 0; t8 < NT; ++t8) {
        int tl = wid * NT + t8;
        if (!sval[tl]) continue;
        float v0 = ptile[tl][lane];                                  // ch 0..63
        float v1 = (lane < CPA - 64) ? ptile[tl][64 + lane] : 0.0f;  // ch 64..84
        // logsumexp over class logits (ch 5..84)
        float m = -INFINITY;
        if (lane >= 5)       m = v0;
        if (lane < CPA - 64) m = fmaxf(m, v1);
        #pragma unroll
        for (int off = 32; off > 0; off >>= 1) m = fmaxf(m, __shfl_xor(m, off));
        float sx = 0.0f, csq = 0.0f;
        if (lane >= 5)       sx += expf(v0 - m);
        if (lane < CPA - 64) sx += expf(v1 - m);
        if (lane < 4) { float d = v0 - stgt[tl][lane]; csq = d * d; }
        #pragma unroll
        for (int off = 32; off > 0; off >>= 1) {
            sx  += __shfl_xor(sx, off);
            csq += __shfl_xor(csq, off);
        }
        float p4 = __shfl(v0, 4);
        int cch  = 5 + scls[tl];
        float pl = (cch < 64) ? __shfl(v0, cch) : __shfl(v1, cch - 64);
        float ce = m + logf(sx) - pl;
        float z  = sigmoidf(p4);
        a_coord += csq;
        a_obj   += softplusf(-z);
        a_noobj += S - softplusf(z);
        a_cls   += ce;
    }

    // ---- one plain 16B store per wave: NO atomics, NO barriers ----
    if (lane == 0 && bv)
        part[bidx] = make_float4(a_coord, a_obj, a_noobj, a_cls);
}

__global__ __launch_bounds__(1024) void yolo_reduce(
    const float4* __restrict__ part, int nb,
    float* __restrict__ out, float denom)
{
    __shared__ float wsum[16][4];
    float c0 = 0.f, c1 = 0.f, c2 = 0.f, c3 = 0.f;
    for (int i = threadIdx.x; i < nb; i += 1024) {
        float4 v = part[i];
        c0 += v.x; c1 += v.y; c2 += v.z; c3 += v.w;
    }
    #pragma unroll
    for (int off = 32; off > 0; off >>= 1) {
        c0 += __shfl_xor(c0, off); c1 += __shfl_xor(c1, off);
        c2 += __shfl_xor(c2, off); c3 += __shfl_xor(c3, off);
    }
    int w = threadIdx.x >> 6;
    if ((threadIdx.x & 63) == 0) {
        wsum[w][0] = c0; wsum[w][1] = c1; wsum[w][2] = c2; wsum[w][3] = c3;
    }
    __syncthreads();
    if (threadIdx.x == 0) {
        float a0 = 0.f, a1 = 0.f, a2 = 0.f, a3 = 0.f;
        #pragma unroll
        for (int i = 0; i < 16; ++i) {
            a0 += wsum[i][0]; a1 += wsum[i][1]; a2 += wsum[i][2]; a3 += wsum[i][3];
        }
        float lc   = a0 / denom;
        float lo   = a1;
        float ln   = 0.5f * a2;
        float lcls = a3 / denom;
        float tot  = 5.0f * lc + lo + 0.5f * ln + lcls;
        out[0] = tot; out[1] = lc; out[2] = lo; out[3] = ln; out[4] = lcls;
    }
}

extern "C" void kernel_launch(void* const* d_in, const int* in_sizes, int n_in,
                              void* d_out, int out_size, void* d_ws, size_t ws_size,
                              hipStream_t stream) {
    const float* preds   = (const float*)d_in[0];
    const float* targets = (const float*)d_in[1];
    const float* anchors = (const float*)d_in[2];
    float*  out  = (float*)d_out;
    float4* part = (float4*)d_ws;          // one float4 per batch, fully overwritten

    int B = in_sizes[0] / SLICE;           // 4096
    int grid = (B + WPB - 1) / WPB;        // one wave per batch

    yolo_main<<<grid, 256, 0, stream>>>(preds, targets, anchors, part, B);
    yolo_reduce<<<1, 1024, 0, stream>>>(part, B, out, (float)B * (float)NT);
}

// Round 8
// 40.802 us; speedup vs baseline: 1.0737x; 1.0304x over previous
//
#include <hip/hip_runtime.h>
#include <math.h>

#define GH 5
#define GW 10
#define HW 50            // GH*GW
#define CPA 85           // channels per anchor (5 + 80)
#define SLICE 12750      // 255 * 50 floats per batch
#define NT 8             // targets per batch
#define IOU_THR 0.3f

__device__ __forceinline__ float softplusf(float x) {
    return fmaxf(x, 0.0f) + log1pf(expf(-fabsf(x)));   // log(1+e^x), stable
}
__device__ __forceinline__ float sigmoidf(float x) {
    return 1.0f / (1.0f + expf(-x));
}

// Two batches per block: more loads in flight per thread, half the
// barrier/epilogue overhead per byte fetched. (Empirical optimum across
// 1/2/4 batches-per-block and a barrier-free wave-private variant — the
// kernel is bound by random 64B-line HBM fetch, not instructions.)
__global__ __launch_bounds__(256) void yolo_main(
    const float* __restrict__ preds,
    const float* __restrict__ targets,
    const float* __restrict__ anchors,
    float* __restrict__ part, int B)   // part[b*4+..] = coord_raw, obj, noobj_raw, cls_raw
{
    __shared__ float ptile[16][88];   // 85 gathered channels x 16 targets (2 batches)
    __shared__ float stgt[16][4];
    __shared__ int   sptr[16];        // element offset of channel-0 for best anchor at cell
    __shared__ int   scls[16];
    __shared__ int   svalid[16];
    __shared__ float Ssh[2];
    __shared__ float wsum[4][2];
    __shared__ float accS[2][4];

    const int  b0   = blockIdx.x * 2;
    const int  b1   = b0 + 1;
    const bool has2 = (b1 < B);
    const int  tid  = threadIdx.x;
    const float* base0 = preds + (size_t)b0 * SLICE;
    const float* base1 = preds + (size_t)(has2 ? b1 : b0) * SLICE;

    if (tid < 8) accS[tid >> 2][tid & 3] = 0.0f;

    // ---- issue obj-channel loads RAW (300 loads, 2 per thread max) ----
    float ov0 = 0.0f, ov1a = 0.0f, ov1b = 0.0f;
    {
        if (tid < 150) {
            int a = tid / 50, yx = tid - a * 50;
            ov0 = base0[(a * CPA + 4) * HW + yx];
        } else {
            int k = tid - 150;                 // 0..105
            int a = k / 50, yx = k - a * 50;
            ov1a = base1[(a * CPA + 4) * HW + yx];
        }
        if (tid < 44) {                        // batch1 idx 106..149
            int k = tid + 106;
            int a = k / 50, yx = k - a * 50;
            ov1b = base1[(a * CPA + 4) * HW + yx];
        }
    }

    // ---- per-target metadata (threads 0..15) ----
    if (tid < 16) {
        int bb = tid >> 3, tt = tid & 7;
        int bidx = bb ? (has2 ? b1 : b0) : b0;
        const float* tg = targets + ((size_t)bidx * NT + tt) * 5;
        float cls = tg[0], tx = tg[1], ty = tg[2], tw = tg[3], th = tg[4];
        int gx = (int)floorf(tx * (float)GW);
        int gy = (int)floorf(ty * (float)GH);
        float best_iou = -1.0f; int best_a = 0;
        #pragma unroll
        for (int a = 0; a < 3; ++a) {
            float aw = anchors[2*a], ah = anchors[2*a+1];
            float inter = fminf(tw, aw) * fminf(th, ah);
            float uni   = tw*th + aw*ah - inter;
            float iou   = inter / (uni + 1e-6f);
            if (iou > best_iou) { best_iou = iou; best_a = a; }  // first-max wins
        }
        int valid = (gx < GW) && (gy < GH) && (best_iou >= IOU_THR) && (bb == 0 || has2);
        int gxc = min(max(gx, 0), GW-1);
        int gyc = min(max(gy, 0), GH-1);
        float aw_s = anchors[2*best_a], ah_s = anchors[2*best_a+1];
        stgt[tid][0] = tx * (float)GW - (float)gx;
        stgt[tid][1] = ty * (float)GH - (float)gy;
        stgt[tid][2] = logf(tw / aw_s + 1e-6f);
        stgt[tid][3] = logf(th / ah_s + 1e-6f);
        scls[tid]   = (int)cls;
        svalid[tid] = valid;
        sptr[tid]   = valid ? (best_a * CPA * HW + gyc * GW + gxc) : 0;
    }
    __syncthreads();

    // ---- direct gather: 1360 scattered loads, 5 unrolled + tail ----
    {
        int i = tid;
        #pragma unroll
        for (int k = 0; k < 5; ++k) {
            int t = i / CPA, cc = i - t * CPA;
            const float* bp = (t >= 8) ? base1 : base0;
            ptile[t][cc] = bp[sptr[t] + cc * HW];
            i += 256;
        }
        if (i < 16 * CPA) {
            int t = i / CPA, cc = i - t * CPA;
            const float* bp = (t >= 8) ? base1 : base0;
            ptile[t][cc] = bp[sptr[t] + cc * HW];
        }
    }

    // ---- obj softplus + reduce S (hides under gather-load latency) ----
    float s0 = 0.0f, s1 = 0.0f;
    if (tid < 150) s0 = softplusf(sigmoidf(ov0));
    else           s1 = softplusf(sigmoidf(ov1a));
    if (tid < 44)  s1 += softplusf(sigmoidf(ov1b));
    #pragma unroll
    for (int off = 32; off > 0; off >>= 1) {
        s0 += __shfl_xor(s0, off);
        s1 += __shfl_xor(s1, off);
    }
    const int wid = tid >> 6, lane = tid & 63;
    if (lane == 0) { wsum[wid][0] = s0; wsum[wid][1] = s1; }
    __syncthreads();            // also publishes ptile
    if (tid < 2) Ssh[tid] = wsum[0][tid] + wsum[1][tid] + wsum[2][tid] + wsum[3][tid];
    __syncthreads();

    // ---- per-target losses: one wave per target (4 waves x 4 rounds) ----
    for (int t = wid; t < 16; t += 4) {
        if (!svalid[t]) continue;
        float v0 = ptile[t][lane];                                  // ch 0..63
        float v1 = (lane < CPA - 64) ? ptile[t][64 + lane] : 0.0f;  // ch 64..84
        float m = -INFINITY;
        if (lane >= 5)        m = v0;
        if (lane < CPA - 64)  m = fmaxf(m, v1);
        #pragma unroll
        for (int off = 32; off > 0; off >>= 1) m = fmaxf(m, __shfl_xor(m, off));
        float s = 0.0f, csq = 0.0f;
        if (lane >= 5)        s += expf(v0 - m);
        if (lane < CPA - 64)  s += expf(v1 - m);
        if (lane < 4) { float d = v0 - stgt[t][lane]; csq = d * d; }
        #pragma unroll
        for (int off = 32; off > 0; off >>= 1) {
            s   += __shfl_xor(s, off);
            csq += __shfl_xor(csq, off);
        }
        float p4 = __shfl(v0, 4);
        int cch = 5 + scls[t];
        float pl = (cch < 64) ? __shfl(v0, cch) : __shfl(v1, cch - 64);
        float ce = m + logf(s) - pl;
        float z    = sigmoidf(p4);
        float spz  = softplusf(z);
        float spnz = softplusf(-z);
        if (lane == 0) {
            int bb = t >> 3;
            atomicAdd(&accS[bb][0], csq);          // LDS atomics — cheap
            atomicAdd(&accS[bb][1], spnz);
            atomicAdd(&accS[bb][2], Ssh[bb] - spz);
            atomicAdd(&accS[bb][3], ce);
        }
    }
    __syncthreads();
    // ---- plain per-block stores: NO global atomics ----
    if (tid < 4)                    part[(size_t)b0 * 4 + tid]       = accS[0][tid];
    else if (tid < 8 && has2)       part[(size_t)b1 * 4 + (tid - 4)] = accS[1][tid - 4];
}

__global__ __launch_bounds__(1024) void yolo_reduce(
    const float4* __restrict__ part, int nb,
    float* __restrict__ out, float denom)
{
    __shared__ float wsum[16][4];
    float c0 = 0.f, c1 = 0.f, c2 = 0.f, c3 = 0.f;
    for (int i = threadIdx.x; i < nb; i += 1024) {
        float4 v = part[i];
        c0 += v.x; c1 += v.y; c2 += v.z; c3 += v.w;
    }
    #pragma unroll
    for (int off = 32; off > 0; off >>= 1) {
        c0 += __shfl_xor(c0, off); c1 += __shfl_xor(c1, off);
        c2 += __shfl_xor(c2, off); c3 += __shfl_xor(c3, off);
    }
    int w = threadIdx.x >> 6;
    if ((threadIdx.x & 63) == 0) {
        wsum[w][0] = c0; wsum[w][1] = c1; wsum[w][2] = c2; wsum[w][3] = c3;
    }
    __syncthreads();
    if (threadIdx.x == 0) {
        float a0 = 0.f, a1 = 0.f, a2 = 0.f, a3 = 0.f;
        #pragma unroll
        for (int i = 0; i < 16; ++i) {
            a0 += wsum[i][0]; a1 += wsum[i][1]; a2 += wsum[i][2]; a3 += wsum[i][3];
        }
        float lc   = a0 / denom;
        float lo   = a1;
        float ln   = 0.5f * a2;
        float lcls = a3 / denom;
        float tot  = 5.0f * lc + lo + 0.5f * ln + lcls;
        out[0] = tot; out[1] = lc; out[2] = lo; out[3] = ln; out[4] = lcls;
    }
}

extern "C" void kernel_launch(void* const* d_in, const int* in_sizes, int n_in,
                              void* d_out, int out_size, void* d_ws, size_t ws_size,
                              hipStream_t stream) {
    const float* preds   = (const float*)d_in[0];
    const float* targets = (const float*)d_in[1];
    const float* anchors = (const float*)d_in[2];
    float* out  = (float*)d_out;
    float* part = (float*)d_ws;           // 4 floats per batch, fully overwritten

    int B = in_sizes[0] / SLICE;   // 4096
    int grid = (B + 1) / 2;        // 2 batches per block

    yolo_main<<<grid, 256, 0, stream>>>(preds, targets, anchors, part, B);
    yolo_reduce<<<1, 1024, 0, stream>>>((const float4*)part, B, out, (float)B * (float)NT);
}